// Round 12
// baseline (295.784 us; speedup 1.0000x reference)
//
#include <hip/hip_runtime.h>

// CrossAttentionPro on MI355X — Round 11:
//  R10 pipeline with the flash_both GRID BUG fixed (512 -> 1024 blocks:
//  att(2) x s-half(2) x q-tiles(16) x z(16); R10's stale "/2" left rows
//  t>=1024 uncomputed -> poison partials -> absmax 4.5e-2).
//  + s-split both flash attentions; partial unnormalized O (f32) + (m,l);
//    combine fused with diff -> DH directly.
//  + exp2-domain softmax (log2e folded into QXs, propagates to Q2).
//  + qkv_x/qkv_y fused into ONE GEMM launch (XH||YH contiguous rows).
// chained = Qx (scale^3 Ky^T Qy) Kx^T; both attentions standard D=64 flash.

typedef _Float16 half_t;
typedef _Float16 half8 __attribute__((ext_vector_type(8)));
typedef _Float16 half4v __attribute__((ext_vector_type(4)));
typedef float floatx4 __attribute__((ext_vector_type(4)));

constexpr int Bc = 2, Tc = 2048, Mc = 1024, Cc = 512, Hc = 8, Dc = 64;
constexpr long BTC = (long)Bc * Tc * Cc;
constexpr long ZT  = (long)Bc * Hc * Tc;          // ML slab stride
constexpr float S1 = 0.18033688f;                 // 0.125 * log2(e)

enum { EPI_F16STORE = 0, EPI_QKV_XY = 1, EPI_PROJ = 2 };

struct EpiParams {
  half_t* h0;        // QXs  / f16 dest
  half_t* h1;        // KX
  half_t* h2;        // VXT
  half_t* h3;        // QYT
  half_t* h4;        // KY
  half_t* h5;        // KYT
  half_t* h6;        // VYT
  float* f0;
  const float* bias;
  float scale;
  int ldc;
  long bstride;
};

// async global->LDS, 16B per lane; dst must be wave-uniform base + lane*16.
__device__ __forceinline__ void gld_lds16(const half_t* g, half_t* l) {
  __builtin_amdgcn_global_load_lds(
      (const __attribute__((address_space(1))) void*)g,
      (__attribute__((address_space(3))) void*)l, 16, 0, 0);
}

// max over each 16-lane row via DPP rotations (VALU pipe, no DS traffic).
__device__ __forceinline__ float rowmax16(float v) {
  union fi { float f; int i; };
#define RMAX_STEP(CTRL)                                                     \
  { fi a; a.f = v; fi b;                                                    \
    b.i = __builtin_amdgcn_update_dpp(a.i, a.i, CTRL, 0xf, 0xf, true);      \
    v = fmaxf(v, b.f); }
  RMAX_STEP(0x121)  // row_ror:1
  RMAX_STEP(0x122)  // row_ror:2
  RMAX_STEP(0x124)  // row_ror:4
  RMAX_STEP(0x128)  // row_ror:8
#undef RMAX_STEP
  return v;
}

// ---------------------------------------------------------------- GEMM (NT)
// R2-proven: C[r,c] = sum_k A[r,k]*Bt[c,k], BK=32 swizzled async staging
// (measured 0 bank conflicts), direct per-element epilogue.
template <int BM, int BN, int WMG, int WNG, int EPI>
__global__ __launch_bounds__(256) void gemm_nt(
    const half_t* __restrict__ A, const half_t* __restrict__ Bt,
    int K, int lda, int ldb, long bsA, long bsB, EpiParams ep)
{
  constexpr int BK = 32;
  constexpr int WTM = BM / WMG, WTN = BN / WNG;
  constexpr int MI = WTM / 16, NI = WTN / 16;
  constexpr int ACHUNKS = BM * 4;
  constexpr int BCHUNKS = BN * 4;
  __shared__ __align__(16) half_t As[BM * BK];
  __shared__ __align__(16) half_t Bs[BN * BK];

  const int tid = threadIdx.x;
  const int lane = tid & 63;
  const int wave = tid >> 6;
  const int wm = wave / WNG, wn = wave % WNG;
  const int r16 = lane & 15, g = lane >> 4;
  const int z = blockIdx.z;
  const long m0 = (long)blockIdx.y * BM;
  const long n0 = (long)blockIdx.x * BN;
  const half_t* Abase = A + (long)z * bsA + m0 * (long)lda;
  const half_t* Bbase = Bt + (long)z * bsB + n0 * (long)ldb;

  const int rA = wm * WTM + r16;
  const int rB = wn * WTN + r16;
  const int swA = (g ^ ((rA >> 1) & 3)) * 8;
  const int swB = (g ^ ((rB >> 1) & 3)) * 8;

  floatx4 acc[MI][NI];
#pragma unroll
  for (int mi = 0; mi < MI; ++mi)
#pragma unroll
    for (int ni = 0; ni < NI; ++ni)
      acc[mi][ni] = floatx4{0.f, 0.f, 0.f, 0.f};

  for (int kt = 0; kt < K; kt += BK) {
#pragma unroll
    for (int i = 0; i < (ACHUNKS + 255) / 256; ++i) {
      const int c = tid + i * 256;
      if (ACHUNKS % 256 == 0 || c < ACHUNKS) {
        const int row = c >> 2, js = c & 3;
        const int jg = js ^ ((row >> 1) & 3);
        gld_lds16(Abase + (long)row * lda + kt + jg * 8, As + c * 8);
      }
    }
#pragma unroll
    for (int i = 0; i < (BCHUNKS + 255) / 256; ++i) {
      const int c = tid + i * 256;
      if (BCHUNKS % 256 == 0 || c < BCHUNKS) {
        const int row = c >> 2, js = c & 3;
        const int jg = js ^ ((row >> 1) & 3);
        gld_lds16(Bbase + (long)row * ldb + kt + jg * 8, Bs + c * 8);
      }
    }
    __syncthreads();
    half8 aF[MI], bF[NI];
#pragma unroll
    for (int mi = 0; mi < MI; ++mi)
      aF[mi] = *reinterpret_cast<const half8*>(&As[(rA + mi * 16) * BK + swA]);
#pragma unroll
    for (int ni = 0; ni < NI; ++ni)
      bF[ni] = *reinterpret_cast<const half8*>(&Bs[(rB + ni * 16) * BK + swB]);
#pragma unroll
    for (int mi = 0; mi < MI; ++mi)
#pragma unroll
      for (int ni = 0; ni < NI; ++ni)
        acc[mi][ni] = __builtin_amdgcn_mfma_f32_16x16x32_f16(aF[mi], bF[ni], acc[mi][ni], 0, 0, 0);
    __syncthreads();
  }

  // epilogue: C/D layout col=lane&15, row=(lane>>4)*4+reg  [m89-verified]
#pragma unroll
  for (int mi = 0; mi < MI; ++mi) {
#pragma unroll
    for (int ni = 0; ni < NI; ++ni) {
#pragma unroll
      for (int reg = 0; reg < 4; ++reg) {
        const int r = (int)m0 + wm * WTM + mi * 16 + g * 4 + reg;
        const int c = (int)n0 + wn * WTN + ni * 16 + r16;
        const float v = acc[mi][ni][reg];
        if constexpr (EPI == EPI_F16STORE) {
          ep.h0[(long)z * ep.bstride + (long)r * ep.ldc + c] = (half_t)(v * ep.scale);
        } else if constexpr (EPI == EPI_QKV_XY) {
          const float val = v + ep.bias[c];
          const int which = c >> 9;     // 0=q 1=k 2=v
          const int cc2 = c & 511;
          const int h = cc2 >> 6, d = cc2 & 63;
          if (r < Bc * Tc) {            // x rows
            const int b = r >> 11, t = r & (Tc - 1);
            const long bh = (long)(b * Hc + h);
            if (which == 0)      ep.h0[(bh * Tc + t) * Dc + d] = (half_t)(val * S1);  // QXs (log2e folded)
            else if (which == 1) ep.h1[(bh * Tc + t) * Dc + d] = (half_t)val;         // KX
            else                 ep.h2[(bh * Dc + d) * Tc + t] = (half_t)val;         // VXT
          } else {                      // y rows
            const int r2 = r - Bc * Tc;
            const int b = r2 >> 10, t = r2 & (Mc - 1);
            const long bh = (long)(b * Hc + h);
            if (which == 0)      ep.h3[(bh * Dc + d) * Mc + t] = (half_t)(val * 0.125f); // QYTs
            else if (which == 1) { ep.h4[(bh * Mc + t) * Dc + d] = (half_t)val;          // KY
                                   ep.h5[(bh * Dc + d) * Mc + t] = (half_t)val; }        // KYT
            else                 ep.h6[(bh * Dc + d) * Mc + t] = (half_t)val;            // VYT
          }
        } else {  // EPI_PROJ
          ep.f0[(long)r * Cc + c] = v + ep.bias[c];
        }
      }
    }
  }
}

// --------------------------------------------------------- flash body (MI=2)
// 128 q-rows/block, s-tiles of 128 over [sbeg, sbeg+scount). Scores are in
// log2 domain (log2e pre-folded into Q). Writes unnormalized partial O (f32)
// and per-row (m,l) for the s-split combine. Row-max via DPP; row-sum via
// ones-MFMA. LDS: uni = Ks staging UNION Ps slabs; Vb = V^T tile.
template <bool MASKED>
__device__ __forceinline__ void flash_body(
    const half_t* __restrict__ Qp, const half_t* __restrict__ Kp,
    const half_t* __restrict__ Vp, const unsigned char* __restrict__ mpk,
    float* __restrict__ PO, float2* __restrict__ ML,
    int Slen, int sbeg, int scount, int bb,
    half_t* uni, half_t* Vb)
{
  const int tid = threadIdx.x, lane = tid & 63, w = tid >> 6;
  const int r16 = lane & 15, g = lane >> 4;
  const int z = ((bb & 7) << 1) | ((bb >> 3) & 1);   // z-local per XCD
  const int q0 = (bb >> 4) * 128;
  const int b = z >> 3, h = z & 7;
  const int NT = Slen >> 7;
  const half_t* Qz = Qp + ((long)z * Tc + q0) * 64;
  const half_t* Kz = Kp + (long)z * Slen * 64;
  const half_t* Vz = Vp + (long)z * 64 * Slen;
  half_t* Ps[2] = { uni + w * 2304, uni + w * 2304 + 1152 };

  half8 aQ[2][2];
#pragma unroll
  for (int mi = 0; mi < 2; ++mi)
#pragma unroll
    for (int k2 = 0; k2 < 2; ++k2)
      aQ[mi][k2] = *reinterpret_cast<const half8*>(
          Qz + (w * 32 + mi * 16 + r16) * 64 + k2 * 32 + g * 8);

  half8 vones;
#pragma unroll
  for (int j = 0; j < 8; ++j) vones[j] = (half_t)1.f;

  floatx4 oacc[2][4], oaccL[2];
  float mrun[2][4];
#pragma unroll
  for (int mi = 0; mi < 2; ++mi) {
    oaccL[mi] = floatx4{0.f, 0.f, 0.f, 0.f};
#pragma unroll
    for (int no = 0; no < 4; ++no) oacc[mi][no] = floatx4{0.f, 0.f, 0.f, 0.f};
#pragma unroll
    for (int reg = 0; reg < 4; ++reg) mrun[mi][reg] = -1e30f;
  }

  for (int s0 = sbeg; s0 < sbeg + scount; s0 += 128) {
    // stage K [128x64] into uni, chunk swizzle js^(row&7)
#pragma unroll
    for (int i = 0; i < 4; ++i) {
      const int c = tid + i * 256;
      const int row = c >> 3, js = c & 7;
      const int jg = js ^ (row & 7);
      gld_lds16(Kz + (long)(s0 + row) * 64 + jg * 8, uni + c * 8);
    }
    // stage V^T [64x128] into Vb, chunk swizzle js^(row&15)
#pragma unroll
    for (int i = 0; i < 4; ++i) {
      const int c = tid + i * 256;
      const int row = c >> 4, js = c & 15;
      const int jg = js ^ (row & 15);
      gld_lds16(Vz + (long)row * Slen + s0 + jg * 8, Vb + c * 8);
    }
    unsigned int mb[2][4];
    if constexpr (MASKED) {
      const int tile = s0 >> 7;
#pragma unroll
      for (int mi = 0; mi < 2; ++mi)
#pragma unroll
        for (int reg = 0; reg < 4; ++reg) {
          const int t = q0 + w * 32 + mi * 16 + g * 4 + reg;
          mb[mi][reg] = mpk[((long)t * NT + tile) * 16 + r16];
        }
    }
    __syncthreads();

    // S = Q K^T : 16 b128 reads feed 32 MFMAs (shared across mi)
    floatx4 sacc[2][8];
#pragma unroll
    for (int mi = 0; mi < 2; ++mi)
#pragma unroll
      for (int ni = 0; ni < 8; ++ni) sacc[mi][ni] = floatx4{0.f, 0.f, 0.f, 0.f};
#pragma unroll
    for (int ni = 0; ni < 8; ++ni) {
      const int rB = ni * 16 + r16;
      const half8 b0 = *reinterpret_cast<const half8*>(&uni[rB * 64 + ((g) ^ (rB & 7)) * 8]);
      const half8 b1 = *reinterpret_cast<const half8*>(&uni[rB * 64 + ((4 + g) ^ (rB & 7)) * 8]);
#pragma unroll
      for (int mi = 0; mi < 2; ++mi) {
        sacc[mi][ni] = __builtin_amdgcn_mfma_f32_16x16x32_f16(aQ[mi][0], b0, sacc[mi][ni], 0, 0, 0);
        sacc[mi][ni] = __builtin_amdgcn_mfma_f32_16x16x32_f16(aQ[mi][1], b1, sacc[mi][ni], 0, 0, 0);
      }
    }
    __syncthreads();   // Ks dead -> uni becomes Ps slabs

    // mask + per-row max (DPP) + alpha rescale (log2 domain)
    if constexpr (MASKED) {
#pragma unroll
      for (int mi = 0; mi < 2; ++mi)
#pragma unroll
        for (int reg = 0; reg < 4; ++reg)
#pragma unroll
          for (int ni = 0; ni < 8; ++ni)
            if (!((mb[mi][reg] >> ni) & 1)) sacc[mi][ni][reg] = -__builtin_inff();
    }
    float al[2][4];
#pragma unroll
    for (int mi = 0; mi < 2; ++mi)
#pragma unroll
      for (int reg = 0; reg < 4; ++reg) {
        float tm = sacc[mi][0][reg];
#pragma unroll
        for (int ni = 1; ni < 8; ++ni) tm = fmaxf(tm, sacc[mi][ni][reg]);
        tm = rowmax16(tm);
        const float mnew = fmaxf(mrun[mi][reg], tm);
        al[mi][reg] = __builtin_amdgcn_exp2f(mrun[mi][reg] - mnew);
        mrun[mi][reg] = mnew;
        oaccL[mi][reg] *= al[mi][reg];
#pragma unroll
        for (int no = 0; no < 4; ++no) oacc[mi][no][reg] *= al[mi][reg];
      }

    // exp2 + P write + PV (+ones row-sum MFMA), two 64-col halves
#pragma unroll
    for (int hf = 0; hf < 2; ++hf) {
#pragma unroll
      for (int mi = 0; mi < 2; ++mi)
#pragma unroll
        for (int reg = 0; reg < 4; ++reg)
#pragma unroll
          for (int ni = 0; ni < 4; ++ni) {
            const float e = __builtin_amdgcn_exp2f(sacc[mi][hf * 4 + ni][reg] - mrun[mi][reg]);
            Ps[mi][(g * 4 + reg) * 72 + ni * 16 + r16] = (half_t)e;
          }
#pragma unroll
      for (int ks2 = 0; ks2 < 2; ++ks2) {
        half8 bV[4];
#pragma unroll
        for (int no = 0; no < 4; ++no) {
          const int rV = no * 16 + r16;
          bV[no] = *reinterpret_cast<const half8*>(
              &Vb[rV * 128 + (((hf * 2 + ks2) * 4 + g) ^ (rV & 15)) * 8]);
        }
#pragma unroll
        for (int mi = 0; mi < 2; ++mi) {
          const half8 aP = *reinterpret_cast<const half8*>(
              &Ps[mi][r16 * 72 + ks2 * 32 + g * 8]);
#pragma unroll
          for (int no = 0; no < 4; ++no)
            oacc[mi][no] = __builtin_amdgcn_mfma_f32_16x16x32_f16(aP, bV[no], oacc[mi][no], 0, 0, 0);
          oaccL[mi] = __builtin_amdgcn_mfma_f32_16x16x32_f16(aP, vones, oaccL[mi], 0, 0, 0);
        }
      }
    }
    __syncthreads();   // Ps/Vb reads done -> restage
  }

  // epilogue: unnormalized O -> PO (f32), stats -> ML
#pragma unroll
  for (int mi = 0; mi < 2; ++mi)
#pragma unroll
    for (int reg = 0; reg < 4; ++reg) {
      const int t = q0 + w * 32 + mi * 16 + g * 4 + reg;
      if (r16 == 0) ML[(long)z * Tc + t] = float2{mrun[mi][reg], oaccL[mi][reg]};
#pragma unroll
      for (int no = 0; no < 4; ++no) {
        const int d = no * 16 + r16;
        PO[((long)(b * Tc + t)) * Cc + h * 64 + d] = oacc[mi][no][reg];
      }
    }
}

// Both attentions x both s-halves in one launch (1024 blocks).
__global__ __launch_bounds__(256) void flash_both(
    const half_t* __restrict__ Q2, const half_t* __restrict__ KX,
    const half_t* __restrict__ VXT, const unsigned char* __restrict__ mpk,
    const half_t* __restrict__ QX, const half_t* __restrict__ KY,
    const half_t* __restrict__ VYT,
    float* __restrict__ PO, float2* __restrict__ ML)
{
  __shared__ __align__(16) half_t uni[9216];
  __shared__ __align__(16) half_t Vb[8192];
  const int bx = blockIdx.x;
  const int att = bx & 1, sh = (bx >> 1) & 1, bb = bx >> 2;
  if (att == 0)
    flash_body<true>(Q2, KX, VXT, mpk, PO + (long)sh * BTC, ML + (long)sh * ZT,
                     Tc, sh * 1024, 1024, bb, uni, Vb);
  else
    flash_body<false>(QX, KY, VYT, nullptr, PO + (long)(2 + sh) * BTC, ML + (long)(2 + sh) * ZT,
                      Mc, sh * 512, 512, bb, uni, Vb);
}

// ------------------------------------- combine s-halves + diff -> DH (f16)
__global__ __launch_bounds__(256) void combine_k(
    const float* __restrict__ PO, const float2* __restrict__ ML,
    half_t* __restrict__ DH)
{
  const long idx = (long)blockIdx.x * 256 + threadIdx.x;   // over BTC/4
  const long c4 = idx * 4;
  const int c = (int)(c4 & (Cc - 1));
  const long bt = c4 >> 9;
  const int h = c >> 6;
  const int b = (int)(bt >> 11), t = (int)(bt & (Tc - 1));
  const long zt = (long)(b * Hc + h) * Tc + t;
  // att0 = chained (cval_y2x), att1 = first (cval_x2y)
  const float2 a0 = ML[zt],          a1 = ML[ZT + zt];
  const float2 b0 = ML[2 * ZT + zt], b1 = ML[3 * ZT + zt];
  const float amm = fmaxf(a0.x, a1.x);
  const float aw0 = __builtin_amdgcn_exp2f(a0.x - amm);
  const float aw1 = __builtin_amdgcn_exp2f(a1.x - amm);
  const float ainv = 1.f / (aw0 * a0.y + aw1 * a1.y);
  const float bmm = fmaxf(b0.x, b1.x);
  const float bw0 = __builtin_amdgcn_exp2f(b0.x - bmm);
  const float bw1 = __builtin_amdgcn_exp2f(b1.x - bmm);
  const float binv = 1.f / (bw0 * b0.y + bw1 * b1.y);
  const float4* PO4 = reinterpret_cast<const float4*>(PO);
  const float4 oa0 = PO4[idx];
  const float4 oa1 = PO4[BTC / 4 + idx];
  const float4 ob0 = PO4[2 * (BTC / 4) + idx];
  const float4 ob1 = PO4[3 * (BTC / 4) + idx];
  half4v r;
  r[0] = (half_t)((ob0.x * bw0 + ob1.x * bw1) * binv - (oa0.x * aw0 + oa1.x * aw1) * ainv);
  r[1] = (half_t)((ob0.y * bw0 + ob1.y * bw1) * binv - (oa0.y * aw0 + oa1.y * aw1) * ainv);
  r[2] = (half_t)((ob0.z * bw0 + ob1.z * bw1) * binv - (oa0.z * aw0 + oa1.z * aw1) * ainv);
  r[3] = (half_t)((ob0.w * bw0 + ob1.w * bw1) * binv - (oa0.w * aw0 + oa1.w * aw1) * ainv);
  reinterpret_cast<half4v*>(DH)[idx] = r;
}

// ----------------------------------------------- prep: converts + mask pack
__device__ __forceinline__ void cvt4(const float* in, half_t* out, long i) {
  const float4 f = reinterpret_cast<const float4*>(in)[i];
  half4v h; h[0] = (half_t)f.x; h[1] = (half_t)f.y; h[2] = (half_t)f.z; h[3] = (half_t)f.w;
  reinterpret_cast<half4v*>(out)[i] = h;
}

__global__ __launch_bounds__(256) void prep(
    const float* __restrict__ x, const float* __restrict__ y,
    const float* __restrict__ qw, const float* __restrict__ pw,
    const int* __restrict__ mask,
    half_t* __restrict__ XH, half_t* __restrict__ YH,
    half_t* __restrict__ WQ, half_t* __restrict__ WP,
    unsigned char* __restrict__ mpk)
{
  const long i = (long)blockIdx.x * 256 + threadIdx.x;
  constexpr long n0 = 524288;            // x/4
  constexpr long n1 = n0 + 262144;       // y/4
  constexpr long n2 = n1 + 196608;       // qkv_w/4
  constexpr long n3 = n2 + 65536;        // proj_w/4
  if (i < n0) cvt4(x, XH, i);
  else if (i < n1) cvt4(y, YH, i - n0);
  else if (i < n2) cvt4(qw, WQ, i - n1);
  else if (i < n3) cvt4(pw, WP, i - n2);
  else {
    const long idx = i - n3;             // [0, Tc*256)
    const int t = (int)(idx >> 8), tile = (int)((idx >> 4) & 15), r16 = (int)(idx & 15);
    const int* row = mask + (long)t * Tc + tile * 128 + r16;
    unsigned int bbits = 0;
#pragma unroll
    for (int ni = 0; ni < 8; ++ni)
      bbits |= (row[ni * 16] != 0 ? 1u : 0u) << ni;
    mpk[idx] = (unsigned char)bbits;
  }
}

// ------------------------------------------------------------- workspace map
constexpr size_t OFF_XH   = 0;                                   // [B*T,C] f16 (YH must follow!)
constexpr size_t OFF_YH   = OFF_XH   + (size_t)Bc*Tc*Cc*2;       // contiguous rows after XH
constexpr size_t OFF_WQ   = OFF_YH   + (size_t)Bc*Mc*Cc*2;
constexpr size_t OFF_WP   = OFF_WQ   + (size_t)3*Cc*Cc*2;
constexpr size_t OFF_QX   = OFF_WP   + (size_t)Cc*Cc*2;          // [z,T,D] *0.125*log2e
constexpr size_t OFF_KX   = OFF_QX   + (size_t)Bc*Hc*Tc*Dc*2;    // [z,T,D]
constexpr size_t OFF_VXT  = OFF_KX   + (size_t)Bc*Hc*Tc*Dc*2;    // [z,D,T]
constexpr size_t OFF_QYT  = OFF_VXT  + (size_t)Bc*Hc*Tc*Dc*2;    // [z,D,M] *0.125
constexpr size_t OFF_KY   = OFF_QYT  + (size_t)Bc*Hc*Mc*Dc*2;    // [z,M,D]
constexpr size_t OFF_KYT  = OFF_KY   + (size_t)Bc*Hc*Mc*Dc*2;    // [z,D,M]
constexpr size_t OFF_VYT  = OFF_KYT  + (size_t)Bc*Hc*Mc*Dc*2;    // [z,D,M]
constexpr size_t OFF_WT   = OFF_VYT  + (size_t)Bc*Hc*Mc*Dc*2;    // [z,64,64]
constexpr size_t OFF_Q2   = OFF_WT   + (size_t)Bc*Hc*Dc*Dc*2;    // [z,T,D]
constexpr size_t OFF_DH   = OFF_Q2   + (size_t)Bc*Hc*Tc*Dc*2;    // [B,T,C] diff f16
constexpr size_t OFF_MPK  = OFF_DH   + (size_t)Bc*Tc*Cc*2;       // [T,16,16] u8
constexpr size_t OFF_PO   = OFF_MPK  + (size_t)Tc*256;           // [4][B,T,C] f32
constexpr size_t OFF_ML   = OFF_PO   + (size_t)4*BTC*4;          // [4][ZT] float2
// total ~80 MB

extern "C" void kernel_launch(void* const* d_in, const int* in_sizes, int n_in,
                              void* d_out, int out_size, void* d_ws, size_t ws_size,
                              hipStream_t stream) {
  const float* x      = (const float*)d_in[0];
  const float* y      = (const float*)d_in[1];
  const int*   mask   = (const int*)  d_in[2];
  const float* qkv_b  = (const float*)d_in[4];
  const float* proj_b = (const float*)d_in[6];
  float* out = (float*)d_out;
  char* ws = (char*)d_ws;

  half_t* XH   = (half_t*)(ws + OFF_XH);
  half_t* YH   = (half_t*)(ws + OFF_YH);
  half_t* WQ   = (half_t*)(ws + OFF_WQ);
  half_t* WP   = (half_t*)(ws + OFF_WP);
  half_t* QX   = (half_t*)(ws + OFF_QX);
  half_t* KX   = (half_t*)(ws + OFF_KX);
  half_t* VXT  = (half_t*)(ws + OFF_VXT);
  half_t* QYT  = (half_t*)(ws + OFF_QYT);
  half_t* KY   = (half_t*)(ws + OFF_KY);
  half_t* KYT  = (half_t*)(ws + OFF_KYT);
  half_t* VYT  = (half_t*)(ws + OFF_VYT);
  half_t* WT   = (half_t*)(ws + OFF_WT);
  half_t* Q2   = (half_t*)(ws + OFF_Q2);
  half_t* DH   = (half_t*)(ws + OFF_DH);
  unsigned char* MPK = (unsigned char*)(ws + OFF_MPK);
  float*  PO   = (float*) (ws + OFF_PO);
  float2* ML   = (float2*)(ws + OFF_ML);

  // converts + mask packing (one launch)
  prep<<<6144, 256, 0, stream>>>(x, y, (const float*)d_in[3], (const float*)d_in[5],
                                 mask, XH, YH, WQ, WP, MPK);

  // fused qkv projection for x and y (XH||YH contiguous: 6144 rows)
  {
    EpiParams ep{};
    ep.h0 = QX; ep.h1 = KX; ep.h2 = VXT; ep.h3 = QYT;
    ep.h4 = KY; ep.h5 = KYT; ep.h6 = VYT; ep.bias = qkv_b;
    gemm_nt<128,128,2,2,EPI_QKV_XY><<<dim3(12, 48, 1), 256, 0, stream>>>(
        XH, WQ, Cc, Cc, Cc, 0, 0, ep);
  }

  // WT[z][d2][d1] = 0.125 * sum_m QYTs[d2,m] KYT[d1,m]
  {
    EpiParams ep{}; ep.h0 = WT; ep.scale = 0.125f; ep.ldc = 64; ep.bstride = 64 * 64;
    gemm_nt<64,64,2,2,EPI_F16STORE><<<dim3(1, 1, Bc*Hc), 256, 0, stream>>>(
        QYT, KYT, Mc, Mc, Mc, (long)Dc*Mc, (long)Dc*Mc, ep);
  }
  // Q2[z][t][d2] = sum_d1 QXs[t,d1] WT[d2,d1]   (inherits log2e from QXs)
  {
    EpiParams ep{}; ep.h0 = Q2; ep.scale = 1.f; ep.ldc = 64; ep.bstride = (long)Tc * 64;
    gemm_nt<128,64,2,2,EPI_F16STORE><<<dim3(1, Tc/128, Bc*Hc), 256, 0, stream>>>(
        QX, WT, Dc, Dc, Dc, (long)Tc*Dc, (long)64*64, ep);
  }

  // both attentions x 2 s-halves: att(2) x sh(2) x q-tiles(16) x z(16) = 1024
  flash_both<<<dim3(2 * 2 * (Tc/128) * (Bc*Hc)), 256, 0, stream>>>(
      Q2, KX, VXT, MPK, QX, KY, VYT, PO, ML);

  // combine halves + diff -> DH
  combine_k<<<(int)(BTC/4/256), 256, 0, stream>>>(PO, ML, DH);

  // out = DH @ proj_w^T + proj_b
  {
    EpiParams ep{}; ep.f0 = out; ep.bias = proj_b;
    gemm_nt<128,64,2,2,EPI_PROJ><<<dim3(8, 32, 1), 256, 0, stream>>>(
        DH, WP, Cc, Cc, Cc, 0, 0, ep);
  }
}

// Round 13
// 228.348 us; speedup vs baseline: 1.2953x; 1.2953x over previous
//
#include <hip/hip_runtime.h>

// CrossAttentionPro on MI355X — Round 12:
//  Balanced 768-block flash schedule (= exactly 3 blocks/CU, one round):
//   att0 (chained, masked): 2 s-halves x 16 q x 16 z = 512 blocks, 8 s-tiles
//        each, partial f32 O + (m,l)  [R11 path]
//   att1 (first): 256 blocks, 8 s-tiles, normalized f16 -> DH2  [R9 path]
//  combine merges att0 halves + diff with DH2 -> DH.
//  Keeps R11 wins: exp2-domain softmax, DPP rowmax, ones-MFMA row-sum,
//  fused qkv, bit-packed mask, XCD z-locality.
// chained = Qx (scale^3 Ky^T Qy) Kx^T; both attentions standard D=64 flash.

typedef _Float16 half_t;
typedef _Float16 half8 __attribute__((ext_vector_type(8)));
typedef _Float16 half4v __attribute__((ext_vector_type(4)));
typedef float floatx4 __attribute__((ext_vector_type(4)));

constexpr int Bc = 2, Tc = 2048, Mc = 1024, Cc = 512, Hc = 8, Dc = 64;
constexpr long BTC = (long)Bc * Tc * Cc;
constexpr long ZT  = (long)Bc * Hc * Tc;          // ML slab stride
constexpr float S1 = 0.18033688f;                 // 0.125 * log2(e)

enum { EPI_F16STORE = 0, EPI_QKV_XY = 1, EPI_PROJ = 2 };

struct EpiParams {
  half_t* h0;        // QXs  / f16 dest
  half_t* h1;        // KX
  half_t* h2;        // VXT
  half_t* h3;        // QYT
  half_t* h4;        // KY
  half_t* h5;        // KYT
  half_t* h6;        // VYT
  float* f0;
  const float* bias;
  float scale;
  int ldc;
  long bstride;
};

// async global->LDS, 16B per lane; dst must be wave-uniform base + lane*16.
__device__ __forceinline__ void gld_lds16(const half_t* g, half_t* l) {
  __builtin_amdgcn_global_load_lds(
      (const __attribute__((address_space(1))) void*)g,
      (__attribute__((address_space(3))) void*)l, 16, 0, 0);
}

// max over each 16-lane row via DPP rotations (VALU pipe, no DS traffic).
__device__ __forceinline__ float rowmax16(float v) {
  union fi { float f; int i; };
#define RMAX_STEP(CTRL)                                                     \
  { fi a; a.f = v; fi b;                                                    \
    b.i = __builtin_amdgcn_update_dpp(a.i, a.i, CTRL, 0xf, 0xf, true);      \
    v = fmaxf(v, b.f); }
  RMAX_STEP(0x121)  // row_ror:1
  RMAX_STEP(0x122)  // row_ror:2
  RMAX_STEP(0x124)  // row_ror:4
  RMAX_STEP(0x128)  // row_ror:8
#undef RMAX_STEP
  return v;
}

// ---------------------------------------------------------------- GEMM (NT)
// R2-proven: C[r,c] = sum_k A[r,k]*Bt[c,k], BK=32 swizzled async staging
// (measured 0 bank conflicts), direct per-element epilogue.
template <int BM, int BN, int WMG, int WNG, int EPI>
__global__ __launch_bounds__(256) void gemm_nt(
    const half_t* __restrict__ A, const half_t* __restrict__ Bt,
    int K, int lda, int ldb, long bsA, long bsB, EpiParams ep)
{
  constexpr int BK = 32;
  constexpr int WTM = BM / WMG, WTN = BN / WNG;
  constexpr int MI = WTM / 16, NI = WTN / 16;
  constexpr int ACHUNKS = BM * 4;
  constexpr int BCHUNKS = BN * 4;
  __shared__ __align__(16) half_t As[BM * BK];
  __shared__ __align__(16) half_t Bs[BN * BK];

  const int tid = threadIdx.x;
  const int lane = tid & 63;
  const int wave = tid >> 6;
  const int wm = wave / WNG, wn = wave % WNG;
  const int r16 = lane & 15, g = lane >> 4;
  const int z = blockIdx.z;
  const long m0 = (long)blockIdx.y * BM;
  const long n0 = (long)blockIdx.x * BN;
  const half_t* Abase = A + (long)z * bsA + m0 * (long)lda;
  const half_t* Bbase = Bt + (long)z * bsB + n0 * (long)ldb;

  const int rA = wm * WTM + r16;
  const int rB = wn * WTN + r16;
  const int swA = (g ^ ((rA >> 1) & 3)) * 8;
  const int swB = (g ^ ((rB >> 1) & 3)) * 8;

  floatx4 acc[MI][NI];
#pragma unroll
  for (int mi = 0; mi < MI; ++mi)
#pragma unroll
    for (int ni = 0; ni < NI; ++ni)
      acc[mi][ni] = floatx4{0.f, 0.f, 0.f, 0.f};

  for (int kt = 0; kt < K; kt += BK) {
#pragma unroll
    for (int i = 0; i < (ACHUNKS + 255) / 256; ++i) {
      const int c = tid + i * 256;
      if (ACHUNKS % 256 == 0 || c < ACHUNKS) {
        const int row = c >> 2, js = c & 3;
        const int jg = js ^ ((row >> 1) & 3);
        gld_lds16(Abase + (long)row * lda + kt + jg * 8, As + c * 8);
      }
    }
#pragma unroll
    for (int i = 0; i < (BCHUNKS + 255) / 256; ++i) {
      const int c = tid + i * 256;
      if (BCHUNKS % 256 == 0 || c < BCHUNKS) {
        const int row = c >> 2, js = c & 3;
        const int jg = js ^ ((row >> 1) & 3);
        gld_lds16(Bbase + (long)row * ldb + kt + jg * 8, Bs + c * 8);
      }
    }
    __syncthreads();
    half8 aF[MI], bF[NI];
#pragma unroll
    for (int mi = 0; mi < MI; ++mi)
      aF[mi] = *reinterpret_cast<const half8*>(&As[(rA + mi * 16) * BK + swA]);
#pragma unroll
    for (int ni = 0; ni < NI; ++ni)
      bF[ni] = *reinterpret_cast<const half8*>(&Bs[(rB + ni * 16) * BK + swB]);
#pragma unroll
    for (int mi = 0; mi < MI; ++mi)
#pragma unroll
      for (int ni = 0; ni < NI; ++ni)
        acc[mi][ni] = __builtin_amdgcn_mfma_f32_16x16x32_f16(aF[mi], bF[ni], acc[mi][ni], 0, 0, 0);
    __syncthreads();
  }

  // epilogue: C/D layout col=lane&15, row=(lane>>4)*4+reg  [m89-verified]
#pragma unroll
  for (int mi = 0; mi < MI; ++mi) {
#pragma unroll
    for (int ni = 0; ni < NI; ++ni) {
#pragma unroll
      for (int reg = 0; reg < 4; ++reg) {
        const int r = (int)m0 + wm * WTM + mi * 16 + g * 4 + reg;
        const int c = (int)n0 + wn * WTN + ni * 16 + r16;
        const float v = acc[mi][ni][reg];
        if constexpr (EPI == EPI_F16STORE) {
          ep.h0[(long)z * ep.bstride + (long)r * ep.ldc + c] = (half_t)(v * ep.scale);
        } else if constexpr (EPI == EPI_QKV_XY) {
          const float val = v + ep.bias[c];
          const int which = c >> 9;     // 0=q 1=k 2=v
          const int cc2 = c & 511;
          const int h = cc2 >> 6, d = cc2 & 63;
          if (r < Bc * Tc) {            // x rows
            const int b = r >> 11, t = r & (Tc - 1);
            const long bh = (long)(b * Hc + h);
            if (which == 0)      ep.h0[(bh * Tc + t) * Dc + d] = (half_t)(val * S1);  // QXs (log2e folded)
            else if (which == 1) ep.h1[(bh * Tc + t) * Dc + d] = (half_t)val;         // KX
            else                 ep.h2[(bh * Dc + d) * Tc + t] = (half_t)val;         // VXT
          } else {                      // y rows
            const int r2 = r - Bc * Tc;
            const int b = r2 >> 10, t = r2 & (Mc - 1);
            const long bh = (long)(b * Hc + h);
            if (which == 0)      ep.h3[(bh * Dc + d) * Mc + t] = (half_t)(val * 0.125f); // QYTs
            else if (which == 1) { ep.h4[(bh * Mc + t) * Dc + d] = (half_t)val;          // KY
                                   ep.h5[(bh * Dc + d) * Mc + t] = (half_t)val; }        // KYT
            else                 ep.h6[(bh * Dc + d) * Mc + t] = (half_t)val;            // VYT
          }
        } else {  // EPI_PROJ
          ep.f0[(long)r * Cc + c] = v + ep.bias[c];
        }
      }
    }
  }
}

// --------------------------------------------------------- flash body (MI=2)
// 128 q-rows/block, s-tiles of 128 over [sbeg, sbeg+scount). Scores in log2
// domain (log2e pre-folded into Q). PARTIAL: write unnormalized O (f32) +
// (m,l). !PARTIAL: normalize and write f16. Row-max via DPP; row-sum via
// ones-MFMA. LDS: uni = Ks staging UNION Ps slabs; Vb = V^T tile.
template <bool MASKED, bool PARTIAL>
__device__ __forceinline__ void flash_body(
    const half_t* __restrict__ Qp, const half_t* __restrict__ Kp,
    const half_t* __restrict__ Vp, const unsigned char* __restrict__ mpk,
    float* __restrict__ PO, float2* __restrict__ ML, half_t* __restrict__ outF,
    int Slen, int sbeg, int scount, int z, int q0,
    half_t* uni, half_t* Vb)
{
  const int tid = threadIdx.x, lane = tid & 63, w = tid >> 6;
  const int r16 = lane & 15, g = lane >> 4;
  const int b = z >> 3, h = z & 7;
  const int NT = Slen >> 7;
  const half_t* Qz = Qp + ((long)z * Tc + q0) * 64;
  const half_t* Kz = Kp + (long)z * Slen * 64;
  const half_t* Vz = Vp + (long)z * 64 * Slen;
  half_t* Ps[2] = { uni + w * 2304, uni + w * 2304 + 1152 };

  half8 aQ[2][2];
#pragma unroll
  for (int mi = 0; mi < 2; ++mi)
#pragma unroll
    for (int k2 = 0; k2 < 2; ++k2)
      aQ[mi][k2] = *reinterpret_cast<const half8*>(
          Qz + (w * 32 + mi * 16 + r16) * 64 + k2 * 32 + g * 8);

  half8 vones;
#pragma unroll
  for (int j = 0; j < 8; ++j) vones[j] = (half_t)1.f;

  floatx4 oacc[2][4], oaccL[2];
  float mrun[2][4];
#pragma unroll
  for (int mi = 0; mi < 2; ++mi) {
    oaccL[mi] = floatx4{0.f, 0.f, 0.f, 0.f};
#pragma unroll
    for (int no = 0; no < 4; ++no) oacc[mi][no] = floatx4{0.f, 0.f, 0.f, 0.f};
#pragma unroll
    for (int reg = 0; reg < 4; ++reg) mrun[mi][reg] = -1e30f;
  }

  for (int s0 = sbeg; s0 < sbeg + scount; s0 += 128) {
    // stage K [128x64] into uni, chunk swizzle js^(row&7)
#pragma unroll
    for (int i = 0; i < 4; ++i) {
      const int c = tid + i * 256;
      const int row = c >> 3, js = c & 7;
      const int jg = js ^ (row & 7);
      gld_lds16(Kz + (long)(s0 + row) * 64 + jg * 8, uni + c * 8);
    }
    // stage V^T [64x128] into Vb, chunk swizzle js^(row&15)
#pragma unroll
    for (int i = 0; i < 4; ++i) {
      const int c = tid + i * 256;
      const int row = c >> 4, js = c & 15;
      const int jg = js ^ (row & 15);
      gld_lds16(Vz + (long)row * Slen + s0 + jg * 8, Vb + c * 8);
    }
    unsigned int mb[2][4];
    if constexpr (MASKED) {
      const int tile = s0 >> 7;
#pragma unroll
      for (int mi = 0; mi < 2; ++mi)
#pragma unroll
        for (int reg = 0; reg < 4; ++reg) {
          const int t = q0 + w * 32 + mi * 16 + g * 4 + reg;
          mb[mi][reg] = mpk[((long)t * NT + tile) * 16 + r16];
        }
    }
    __syncthreads();

    // S = Q K^T : 16 b128 reads feed 32 MFMAs (shared across mi)
    floatx4 sacc[2][8];
#pragma unroll
    for (int mi = 0; mi < 2; ++mi)
#pragma unroll
      for (int ni = 0; ni < 8; ++ni) sacc[mi][ni] = floatx4{0.f, 0.f, 0.f, 0.f};
#pragma unroll
    for (int ni = 0; ni < 8; ++ni) {
      const int rB = ni * 16 + r16;
      const half8 b0 = *reinterpret_cast<const half8*>(&uni[rB * 64 + ((g) ^ (rB & 7)) * 8]);
      const half8 b1 = *reinterpret_cast<const half8*>(&uni[rB * 64 + ((4 + g) ^ (rB & 7)) * 8]);
#pragma unroll
      for (int mi = 0; mi < 2; ++mi) {
        sacc[mi][ni] = __builtin_amdgcn_mfma_f32_16x16x32_f16(aQ[mi][0], b0, sacc[mi][ni], 0, 0, 0);
        sacc[mi][ni] = __builtin_amdgcn_mfma_f32_16x16x32_f16(aQ[mi][1], b1, sacc[mi][ni], 0, 0, 0);
      }
    }
    __syncthreads();   // Ks dead -> uni becomes Ps slabs

    // mask + per-row max (DPP) + alpha rescale (log2 domain)
    if constexpr (MASKED) {
#pragma unroll
      for (int mi = 0; mi < 2; ++mi)
#pragma unroll
        for (int reg = 0; reg < 4; ++reg)
#pragma unroll
          for (int ni = 0; ni < 8; ++ni)
            if (!((mb[mi][reg] >> ni) & 1)) sacc[mi][ni][reg] = -__builtin_inff();
    }
    float al[2][4];
#pragma unroll
    for (int mi = 0; mi < 2; ++mi)
#pragma unroll
      for (int reg = 0; reg < 4; ++reg) {
        float tm = sacc[mi][0][reg];
#pragma unroll
        for (int ni = 1; ni < 8; ++ni) tm = fmaxf(tm, sacc[mi][ni][reg]);
        tm = rowmax16(tm);
        const float mnew = fmaxf(mrun[mi][reg], tm);
        al[mi][reg] = __builtin_amdgcn_exp2f(mrun[mi][reg] - mnew);
        mrun[mi][reg] = mnew;
        oaccL[mi][reg] *= al[mi][reg];
#pragma unroll
        for (int no = 0; no < 4; ++no) oacc[mi][no][reg] *= al[mi][reg];
      }

    // exp2 + P write + PV (+ones row-sum MFMA), two 64-col halves
#pragma unroll
    for (int hf = 0; hf < 2; ++hf) {
#pragma unroll
      for (int mi = 0; mi < 2; ++mi)
#pragma unroll
        for (int reg = 0; reg < 4; ++reg)
#pragma unroll
          for (int ni = 0; ni < 4; ++ni) {
            const float e = __builtin_amdgcn_exp2f(sacc[mi][hf * 4 + ni][reg] - mrun[mi][reg]);
            Ps[mi][(g * 4 + reg) * 72 + ni * 16 + r16] = (half_t)e;
          }
#pragma unroll
      for (int ks2 = 0; ks2 < 2; ++ks2) {
        half8 bV[4];
#pragma unroll
        for (int no = 0; no < 4; ++no) {
          const int rV = no * 16 + r16;
          bV[no] = *reinterpret_cast<const half8*>(
              &Vb[rV * 128 + (((hf * 2 + ks2) * 4 + g) ^ (rV & 15)) * 8]);
        }
#pragma unroll
        for (int mi = 0; mi < 2; ++mi) {
          const half8 aP = *reinterpret_cast<const half8*>(
              &Ps[mi][r16 * 72 + ks2 * 32 + g * 8]);
#pragma unroll
          for (int no = 0; no < 4; ++no)
            oacc[mi][no] = __builtin_amdgcn_mfma_f32_16x16x32_f16(aP, bV[no], oacc[mi][no], 0, 0, 0);
          oaccL[mi] = __builtin_amdgcn_mfma_f32_16x16x32_f16(aP, vones, oaccL[mi], 0, 0, 0);
        }
      }
    }
    __syncthreads();   // Ps/Vb reads done -> restage
  }

  // epilogue
#pragma unroll
  for (int mi = 0; mi < 2; ++mi)
#pragma unroll
    for (int reg = 0; reg < 4; ++reg) {
      const int t = q0 + w * 32 + mi * 16 + g * 4 + reg;
      if constexpr (PARTIAL) {
        if (r16 == 0) ML[(long)z * Tc + t] = float2{mrun[mi][reg], oaccL[mi][reg]};
#pragma unroll
        for (int no = 0; no < 4; ++no) {
          const int d = no * 16 + r16;
          PO[((long)(b * Tc + t)) * Cc + h * 64 + d] = oacc[mi][no][reg];
        }
      } else {
        const float linv = 1.f / oaccL[mi][reg];
#pragma unroll
        for (int no = 0; no < 4; ++no) {
          const int d = no * 16 + r16;
          outF[((long)(b * Tc + t)) * Cc + h * 64 + d] = (half_t)(oacc[mi][no][reg] * linv);
        }
      }
    }
}

// 768 blocks, each exactly 8 s-tiles (= 3 blocks/CU, one balanced round):
//  bx < 512:  att0 (chained, masked), s-half sh=(bx>>4)&1, partial f32
//  bx >= 512: att1 (first), full s-range, normalized f16 -> DH2
__global__ __launch_bounds__(256) void flash_both(
    const half_t* __restrict__ Q2, const half_t* __restrict__ KX,
    const half_t* __restrict__ VXT, const unsigned char* __restrict__ mpk,
    const half_t* __restrict__ QX, const half_t* __restrict__ KY,
    const half_t* __restrict__ VYT,
    float* __restrict__ PO, float2* __restrict__ ML, half_t* __restrict__ DH2)
{
  __shared__ __align__(16) half_t uni[9216];
  __shared__ __align__(16) half_t Vb[8192];
  const int bx = blockIdx.x;
  if (bx < 512) {
    const int z  = ((bx & 7) << 1) | ((bx >> 3) & 1);   // z-local per XCD
    const int sh = (bx >> 4) & 1;
    const int q0 = (bx >> 5) * 128;
    flash_body<true, true>(Q2, KX, VXT, mpk,
                           PO + (long)sh * BTC, ML + (long)sh * ZT, nullptr,
                           Tc, sh * 1024, 1024, z, q0, uni, Vb);
  } else {
    const int b2 = bx - 512;
    const int z  = ((b2 & 7) << 1) | ((b2 >> 3) & 1);
    const int q0 = (b2 >> 4) * 128;
    flash_body<false, false>(QX, KY, VYT, nullptr,
                             nullptr, nullptr, DH2,
                             Mc, 0, Mc, z, q0, uni, Vb);
  }
}

// --------------------------- combine att0 s-halves + diff with DH2 -> DH
__global__ __launch_bounds__(256) void combine_k(
    const float* __restrict__ PO, const float2* __restrict__ ML,
    const half_t* __restrict__ DH2, half_t* __restrict__ DH)
{
  const long idx = (long)blockIdx.x * 256 + threadIdx.x;   // over BTC/4
  const long c4 = idx * 4;
  const int c = (int)(c4 & (Cc - 1));
  const long bt = c4 >> 9;
  const int h = c >> 6;
  const int b = (int)(bt >> 11), t = (int)(bt & (Tc - 1));
  const long zt = (long)(b * Hc + h) * Tc + t;
  const float2 a0 = ML[zt], a1 = ML[ZT + zt];
  const float amm = fmaxf(a0.x, a1.x);
  const float aw0 = __builtin_amdgcn_exp2f(a0.x - amm);
  const float aw1 = __builtin_amdgcn_exp2f(a1.x - amm);
  const float ainv = 1.f / (aw0 * a0.y + aw1 * a1.y);
  const float4* PO4 = reinterpret_cast<const float4*>(PO);
  const float4 oa0 = PO4[idx];
  const float4 oa1 = PO4[BTC / 4 + idx];
  const half4v dv = reinterpret_cast<const half4v*>(DH2)[idx];
  half4v r;
  r[0] = (half_t)((float)dv[0] - (oa0.x * aw0 + oa1.x * aw1) * ainv);
  r[1] = (half_t)((float)dv[1] - (oa0.y * aw0 + oa1.y * aw1) * ainv);
  r[2] = (half_t)((float)dv[2] - (oa0.z * aw0 + oa1.z * aw1) * ainv);
  r[3] = (half_t)((float)dv[3] - (oa0.w * aw0 + oa1.w * aw1) * ainv);
  reinterpret_cast<half4v*>(DH)[idx] = r;
}

// ----------------------------------------------- prep: converts + mask pack
__device__ __forceinline__ void cvt4(const float* in, half_t* out, long i) {
  const float4 f = reinterpret_cast<const float4*>(in)[i];
  half4v h; h[0] = (half_t)f.x; h[1] = (half_t)f.y; h[2] = (half_t)f.z; h[3] = (half_t)f.w;
  reinterpret_cast<half4v*>(out)[i] = h;
}

__global__ __launch_bounds__(256) void prep(
    const float* __restrict__ x, const float* __restrict__ y,
    const float* __restrict__ qw, const float* __restrict__ pw,
    const int* __restrict__ mask,
    half_t* __restrict__ XH, half_t* __restrict__ YH,
    half_t* __restrict__ WQ, half_t* __restrict__ WP,
    unsigned char* __restrict__ mpk)
{
  const long i = (long)blockIdx.x * 256 + threadIdx.x;
  constexpr long n0 = 524288;            // x/4
  constexpr long n1 = n0 + 262144;       // y/4
  constexpr long n2 = n1 + 196608;       // qkv_w/4
  constexpr long n3 = n2 + 65536;        // proj_w/4
  if (i < n0) cvt4(x, XH, i);
  else if (i < n1) cvt4(y, YH, i - n0);
  else if (i < n2) cvt4(qw, WQ, i - n1);
  else if (i < n3) cvt4(pw, WP, i - n2);
  else {
    const long idx = i - n3;             // [0, Tc*256)
    const int t = (int)(idx >> 8), tile = (int)((idx >> 4) & 15), r16 = (int)(idx & 15);
    const int* row = mask + (long)t * Tc + tile * 128 + r16;
    unsigned int bbits = 0;
#pragma unroll
    for (int ni = 0; ni < 8; ++ni)
      bbits |= (row[ni * 16] != 0 ? 1u : 0u) << ni;
    mpk[idx] = (unsigned char)bbits;
  }
}

// ------------------------------------------------------------- workspace map
constexpr size_t OFF_XH   = 0;                                   // [B*T,C] f16 (YH must follow!)
constexpr size_t OFF_YH   = OFF_XH   + (size_t)Bc*Tc*Cc*2;       // contiguous rows after XH
constexpr size_t OFF_WQ   = OFF_YH   + (size_t)Bc*Mc*Cc*2;
constexpr size_t OFF_WP   = OFF_WQ   + (size_t)3*Cc*Cc*2;
constexpr size_t OFF_QX   = OFF_WP   + (size_t)Cc*Cc*2;          // [z,T,D] *0.125*log2e
constexpr size_t OFF_KX   = OFF_QX   + (size_t)Bc*Hc*Tc*Dc*2;    // [z,T,D]
constexpr size_t OFF_VXT  = OFF_KX   + (size_t)Bc*Hc*Tc*Dc*2;    // [z,D,T]
constexpr size_t OFF_QYT  = OFF_VXT  + (size_t)Bc*Hc*Tc*Dc*2;    // [z,D,M] *0.125
constexpr size_t OFF_KY   = OFF_QYT  + (size_t)Bc*Hc*Mc*Dc*2;    // [z,M,D]
constexpr size_t OFF_KYT  = OFF_KY   + (size_t)Bc*Hc*Mc*Dc*2;    // [z,D,M]
constexpr size_t OFF_VYT  = OFF_KYT  + (size_t)Bc*Hc*Mc*Dc*2;    // [z,D,M]
constexpr size_t OFF_WT   = OFF_VYT  + (size_t)Bc*Hc*Mc*Dc*2;    // [z,64,64]
constexpr size_t OFF_Q2   = OFF_WT   + (size_t)Bc*Hc*Dc*Dc*2;    // [z,T,D]
constexpr size_t OFF_DH   = OFF_Q2   + (size_t)Bc*Hc*Tc*Dc*2;    // [B,T,C] diff f16
constexpr size_t OFF_DH2  = OFF_DH   + (size_t)Bc*Tc*Cc*2;       // [B,T,C] cval_x2y f16
constexpr size_t OFF_MPK  = OFF_DH2  + (size_t)Bc*Tc*Cc*2;       // [T,16,16] u8
constexpr size_t OFF_PO   = OFF_MPK  + (size_t)Tc*256;           // [2][B,T,C] f32
constexpr size_t OFF_ML   = OFF_PO   + (size_t)2*BTC*4;          // [2][ZT] float2
// total ~70 MB

extern "C" void kernel_launch(void* const* d_in, const int* in_sizes, int n_in,
                              void* d_out, int out_size, void* d_ws, size_t ws_size,
                              hipStream_t stream) {
  const float* x      = (const float*)d_in[0];
  const float* y      = (const float*)d_in[1];
  const int*   mask   = (const int*)  d_in[2];
  const float* qkv_b  = (const float*)d_in[4];
  const float* proj_b = (const float*)d_in[6];
  float* out = (float*)d_out;
  char* ws = (char*)d_ws;

  half_t* XH   = (half_t*)(ws + OFF_XH);
  half_t* YH   = (half_t*)(ws + OFF_YH);
  half_t* WQ   = (half_t*)(ws + OFF_WQ);
  half_t* WP   = (half_t*)(ws + OFF_WP);
  half_t* QX   = (half_t*)(ws + OFF_QX);
  half_t* KX   = (half_t*)(ws + OFF_KX);
  half_t* VXT  = (half_t*)(ws + OFF_VXT);
  half_t* QYT  = (half_t*)(ws + OFF_QYT);
  half_t* KY   = (half_t*)(ws + OFF_KY);
  half_t* KYT  = (half_t*)(ws + OFF_KYT);
  half_t* VYT  = (half_t*)(ws + OFF_VYT);
  half_t* WT   = (half_t*)(ws + OFF_WT);
  half_t* Q2   = (half_t*)(ws + OFF_Q2);
  half_t* DH   = (half_t*)(ws + OFF_DH);
  half_t* DH2  = (half_t*)(ws + OFF_DH2);
  unsigned char* MPK = (unsigned char*)(ws + OFF_MPK);
  float*  PO   = (float*) (ws + OFF_PO);
  float2* ML   = (float2*)(ws + OFF_ML);

  // converts + mask packing (one launch)
  prep<<<6144, 256, 0, stream>>>(x, y, (const float*)d_in[3], (const float*)d_in[5],
                                 mask, XH, YH, WQ, WP, MPK);

  // fused qkv projection for x and y (XH||YH contiguous: 6144 rows)
  {
    EpiParams ep{};
    ep.h0 = QX; ep.h1 = KX; ep.h2 = VXT; ep.h3 = QYT;
    ep.h4 = KY; ep.h5 = KYT; ep.h6 = VYT; ep.bias = qkv_b;
    gemm_nt<128,128,2,2,EPI_QKV_XY><<<dim3(12, 48, 1), 256, 0, stream>>>(
        XH, WQ, Cc, Cc, Cc, 0, 0, ep);
  }

  // WT[z][d2][d1] = 0.125 * sum_m QYTs[d2,m] KYT[d1,m]
  {
    EpiParams ep{}; ep.h0 = WT; ep.scale = 0.125f; ep.ldc = 64; ep.bstride = 64 * 64;
    gemm_nt<64,64,2,2,EPI_F16STORE><<<dim3(1, 1, Bc*Hc), 256, 0, stream>>>(
        QYT, KYT, Mc, Mc, Mc, (long)Dc*Mc, (long)Dc*Mc, ep);
  }
  // Q2[z][t][d2] = sum_d1 QXs[t,d1] WT[d2,d1]   (inherits log2e from QXs)
  {
    EpiParams ep{}; ep.h0 = Q2; ep.scale = 1.f; ep.ldc = 64; ep.bstride = (long)Tc * 64;
    gemm_nt<128,64,2,2,EPI_F16STORE><<<dim3(1, Tc/128, Bc*Hc), 256, 0, stream>>>(
        QX, WT, Dc, Dc, Dc, (long)Tc*Dc, (long)64*64, ep);
  }

  // balanced flash: 512 att0-half blocks + 256 att1 blocks = 768 (3/CU)
  flash_both<<<dim3(768), 256, 0, stream>>>(
      Q2, KX, VXT, MPK, QX, KY, VYT, PO, ML, DH2);

  // combine att0 halves + diff with DH2 -> DH
  combine_k<<<(int)(BTC/4/256), 256, 0, stream>>>(PO, ML, DH2, DH);

  // out = DH @ proj_w^T + proj_b
  {
    EpiParams ep{}; ep.f0 = out; ep.bias = proj_b;
    gemm_nt<128,64,2,2,EPI_PROJ><<<dim3(8, 32, 1), 256, 0, stream>>>(
        DH, WP, Cc, Cc, Cc, 0, 0, ep);
  }
}